// Round 1
// baseline (108.471 us; speedup 1.0000x reference)
//
#include <hip/hip_runtime.h>

#define PRECS 1e-6f

// raw hardware transcendentals: v_exp_f32 / v_log_f32 (base-2).
// fpow(0, e>0) == 0 exactly: log2(0)=-inf -> exp2(-inf)=0.
__device__ __forceinline__ float fpow(float b, float e) {
    return __builtin_amdgcn_exp2f(e * __builtin_amdgcn_logf(b));
}

__device__ __forceinline__ float frcp(float v) {
    return __builtin_amdgcn_rcpf(v);
}

template <int CTRL>
__device__ __forceinline__ float dpp_mov(float v) {
    return __int_as_float(
        __builtin_amdgcn_update_dpp(0, __float_as_int(v), CTRL, 0xF, 0xF, true));
}

// sum over each 8-lane group, entirely on the VALU pipe (DPP, no LDS)
__device__ __forceinline__ float rsum8(float v) {
    v += dpp_mov<0xB1>(v);   // quad_perm [1,0,3,2]  : lane ^= 1
    v += dpp_mov<0x4E>(v);   // quad_perm [2,3,0,1]  : lane ^= 2
    v += dpp_mov<0x141>(v);  // row_half_mirror      : lane -> 7-lane within 8
    return v;
}

__global__ __launch_bounds__(64) void xaj_kernel(
    const float* __restrict__ x,     // (365, 2000, 3)
    const float* __restrict__ prm,   // (2000, 12, 8)
    float* __restrict__ out)         // (365, 2000, 5)
{
    constexpr int Nstep = 365, Ngrid = 2000;
    constexpr int xstride = Ngrid * 3;
    const int tid = blockIdx.x * 64 + threadIdx.x;   // grid=250, block=64 -> exactly 16000
    const int g = tid >> 3;
    const int m = tid & 7;

    const float lo[12] = {0.3f,0.0f,0.01f,0.01f,0.01f,0.09f,0.01f,0.0f,0.01f,0.01f,0.0f,0.0f};
    const float hi[12] = {2.0f,5.0f,100.0f,100.0f,200.0f,1.0f,100.0f,10.0f,0.7f,0.7f,0.998f,0.998f};
    float p[12];
    const float* pb = prm + (size_t)g * 96 + m;
#pragma unroll
    for (int i = 0; i < 12; ++i)
        p[i] = lo[i] + pb[i * 8] * (hi[i] - lo[i]);

    const float KE=p[0], B=p[1], WUM=p[2], WLM=p[3], WM=p[4], C=p[5],
                SM=p[6], EX=p[7], KI_=p[8], KG_=p[9], CI=p[10], CG=p[11];

    // loop-invariant derived constants
    const float wdm  = fmaxf(WM - WUM - WLM, 0.f);
    const float sumk = KI_ + KG_;
    const float nrm  = (1.f - PRECS) / (sumk + PRECS);
    const float KI   = (sumk < 1.f) ? KI_ : KI_ * nrm;
    const float KG   = (sumk < 1.f) ? KG_ : KG_ * nrm;
    const float expB = 1.f + B,  invB  = 1.f / expB;
    const float WMM  = WM * expB;
    const float expEX= 1.f + EX, invEX = 1.f / expEX;
    const float SMM  = SM * expEX;
    const float inv_WLM = 1.f / (WLM + PRECS);
    const float inv_WM  = 1.f / (WM  + PRECS);
    const float inv_WMM = 1.f / (WMM + PRECS);
    const float inv_SM  = 1.f / (SM  + PRECS);
    const float inv_SMM = 1.f / (SMM + PRECS);
    const float oneK = 1.f - KI - KG;
    const float omCI = 1.f - CI, omCG = 1.f - CG;
    const float CWLM = C * WLM;
    const float inv1p = 1.f / (1.f + PRECS);
    // exact floor of ratio_s when S_eq hits the SM clamp: 1 - SM*inv_SM
    const float eps2  = fmaxf(PRECS, fmaf(-SM, inv_SM, 1.f));

    // per-lane output weights: col = min(m,4); lanes 4..7 duplicate col 4
    const float wa = (m == 0 || m == 1) ? 0.125f : 0.f;
    const float wb = (m == 0 || m == 2) ? 0.125f : 0.f;
    const float wc = (m == 0 || m == 3) ? 0.125f : 0.f;
    const float wd = (m >= 4) ? 0.125f : 0.f;
    const int   col = (m < 4) ? m : 4;
    float* outp = out + (size_t)g * 5 + col;
    const size_t ostr = (size_t)Ngrid * 5;

    // carry state. W-chain: WU/WL/WD.  S-chain: S, FR0, iFR0, QI, QG.
    float WU=0.001f, WL=0.001f, WD=0.001f;
    float S=0.001f, FR0=0.001f, QI=0.001f, QG=0.001f;
    float iFR0 = frcp(FR0 + PRECS);

    // stash handed from A(t) to B(t) (B runs one loop body later)
    float sPE, sRp, sE, sFRn, siFRn;

    // 4-step-ahead prefetch of P / PET
    const float* xg = x + (size_t)g * 3;
    float Pf0 = xg[0],            Ef0 = xg[2];
    float Pf1 = xg[xstride],      Ef1 = xg[xstride + 2];
    float Pf2 = xg[2 * xstride],  Ef2 = xg[2 * xstride + 2];
    float Pf3 = xg[3 * xstride],  Ef3 = xg[3 * xstride + 2];

    // ---- A: W-chain for step t. Reads/writes WU,WL,WD only; emits stash. ----
    auto Ablock = [&](float Pt, float PETr) {
        const float PET_t = PETr * KE;
        // evaporation cascade. D = relu(PET - P - WU) is exact:
        // max(PET - min(PET, WU+P), 0) == relu(PET - P - WU)
        const float EU = fminf(PET_t, WU + Pt);
        const float D  = fmaxf(PET_t - Pt - WU, 0.f);
        // WL-only side (off D's path)
        const float we = fmaxf(WL - CWLM, 0.f);
        const float wr = we * frcp(we + 1.f);
        const float cwet = wr * WL * inv_WLM;   // wr*EL_wet = cwet*D
        const float omwr = 1.f - wr;
        const float ELdry = fminf(C * D, WL);
        const float EL = fminf(fmaxf(fmaf(omwr, ELdry, cwet * D), 0.f), WL);
        const float ED = fminf(C * fmaxf(D - EL, 0.f), WD);
        const float E  = EU + EL + ED;
        const float PE = fmaxf(Pt - E, 0.f);

        // runoff generation; omr = relu(pow1 - PE/WMM) == relu(1-(PE+A)/WMM)
        // up to eps=PRECS/WMM (R_per error <= PRECS)
        const float W = WU + WL + WD;
        const float base_W = fmaxf(fmaf(-W, inv_WM, 1.f), PRECS);
        const float pw1 = fpow(base_W, invB);
        const float omr = fmaxf(fmaf(-PE, inv_WMM, pw1), 0.f);
        const float R_per = fmaxf(fmaf(WM, fpow(omr, expB), PE + (W - WM)), 0.f);

        // soil-moisture bookkeeping: parallel fill/sub chains + sign select.
        const float dW = Pt - E - R_per;
        const float cum0 = WU + dW;
        const float WUf  = fminf(cum0, WUM);
        const float cum1 = WL + (cum0 - WUf);
        const float WLf  = fminf(cum1, WLM);
        const float cum2 = WD + (cum1 - WLf);
        const float WDf  = fminf(cum2, fmaxf(wdm, WD));
        const float dneg = -dW;
        const float WUs  = fmaxf(WU - dneg, 0.f);
        const float r1   = fmaxf(dneg - WU, 0.f);
        const float WLs  = fmaxf(WL - r1, 0.f);
        const float r2   = fmaxf(r1 - WL, 0.f);
        const float WDs  = fmaxf(WD - r2, 0.f);
        const bool pos = dW >= 0.f;
        WU = pos ? WUf : WUs;
        WL = pos ? WLf : WLs;
        WD = pos ? WDf : WDs;

        // FR candidates for B. rcp(min(aa,1)+PRECS) == max(rcp(aa+PRECS), inv1p)
        const float q  = frcp(PE + PRECS);
        const float aa = R_per * q;
        sFRn  = fminf(aa, 1.f);
        siFRn = fmaxf(frcp(aa + PRECS), inv1p);
        sPE = PE; sRp = R_per; sE = E;
    };

    // ---- B: S-chain for the stashed step + reduction + store. ----
    auto Bblock = [&](float* orow) {
        const float PE = sPE, R_per = sRp;
        const bool wet = PE > 0.f;
        const float FR  = wet ? sFRn  : FR0;
        const float iFR = wet ? siFRn : iFR0;   // rcp(FR+PRECS), FR0-branch carried free
        const float sf  = S * FR0;              // previous-iteration values: off-chain
        const float sf2 = sf * inv_SM;
        const float S_eq = fminf(sf * iFR, SM);
        // exact refactor: max(1 - min(sf*iFR,SM)*inv_SM, PRECS)
        //              == max(1 - sf2*iFR, max(PRECS, 1-SM*inv_SM))
        const float ratio_s = fmaxf(fmaf(-sf2, iFR, 1.f), eps2);
        const float u   = fpow(ratio_s, invEX);
        // om2 = relu(u - PE/SMM) == relu(1-(PE+AU)/SMM) up to PRECS-level error
        const float om2 = fmaxf(fmaf(-PE, inv_SMM, u), 0.f);
        const float base = (PE - SM) + S_eq;
        float RS = fmaf(SM, fpow(om2, expEX), base) * FR;
        RS = __builtin_amdgcn_fmed3f(RS, 0.f, R_per);   // clamp [0, R_per]
        const float Sn = fminf(fmaf(R_per - RS, iFR, S_eq), SM);
        const float RI = (KI * FR) * Sn;
        const float RG = (KG * FR) * Sn;
        S  = Sn * oneK;
        QI = fmaf(omCI, RI, CI * QI);
        QG = fmaf(omCG, RG, CG * QG);
        FR0 = FR; iFR0 = iFR;

        // mean over mu (8 lanes per grid) on the VALU pipe; all lanes store
        const float u0 = rsum8(RS);
        const float u1 = rsum8(QI);
        const float u2 = rsum8(QG);
        const float u3 = rsum8(sE);
        *orow = fmaf(u0, wa, fmaf(u1, wb, fmaf(u2, wc, u3 * wd)));
    };

    // prologue: A(0)
    Ablock(Pf0, Ef0);
    Pf0 = Pf1; Ef0 = Ef1; Pf1 = Pf2; Ef1 = Ef2; Pf2 = Pf3; Ef2 = Ef3;
    {
        const float* xq = xg + (size_t)4 * xstride;
        Pf3 = xq[0]; Ef3 = xq[2];
    }

    // software-pipelined main loop: body = [B(t-1) ; A(t)] — the two are
    // data-independent, so the scheduler can interleave B's pow/rcp stalls
    // with A's cascade and vice versa.
#pragma unroll 2
    for (int t = 1; t < Nstep; ++t) {
        Bblock(outp + (size_t)(t - 1) * ostr);
        Ablock(Pf0, Ef0);
        Pf0 = Pf1; Ef0 = Ef1; Pf1 = Pf2; Ef1 = Ef2; Pf2 = Pf3; Ef2 = Ef3;
        const int tn = (t + 4 < Nstep) ? t + 4 : Nstep - 1;
        const float* xq = xg + (size_t)tn * xstride;
        Pf3 = xq[0]; Ef3 = xq[2];
    }
    // epilogue: B(364)
    Bblock(outp + (size_t)(Nstep - 1) * ostr);
}

extern "C" void kernel_launch(void* const* d_in, const int* in_sizes, int n_in,
                              void* d_out, int out_size, void* d_ws, size_t ws_size,
                              hipStream_t stream) {
    const float* x   = (const float*)d_in[0];
    const float* prm = (const float*)d_in[1];
    float* out = (float*)d_out;
    xaj_kernel<<<250, 64, 0, stream>>>(x, prm, out);
}

// Round 2
// 107.293 us; speedup vs baseline: 1.0110x; 1.0110x over previous
//
#include <hip/hip_runtime.h>

#define PRECS 1e-6f

// raw hardware transcendentals: v_exp_f32 / v_log_f32 (base-2).
// fpow(0, e>0) == 0 exactly: log2(0)=-inf -> exp2(-inf)=0.
__device__ __forceinline__ float fpow(float b, float e) {
    return __builtin_amdgcn_exp2f(e * __builtin_amdgcn_logf(b));
}

__device__ __forceinline__ float frcp(float v) {
    return __builtin_amdgcn_rcpf(v);
}

template <int CTRL>
__device__ __forceinline__ float dpp_mov(float v) {
    return __int_as_float(
        __builtin_amdgcn_update_dpp(0, __float_as_int(v), CTRL, 0xF, 0xF, true));
}

// sum over each 8-lane group, entirely on the VALU pipe (DPP, no LDS)
__device__ __forceinline__ float rsum8(float v) {
    v += dpp_mov<0xB1>(v);   // quad_perm [1,0,3,2]  : lane ^= 1
    v += dpp_mov<0x4E>(v);   // quad_perm [2,3,0,1]  : lane ^= 2
    v += dpp_mov<0x141>(v);  // row_half_mirror      : lane -> 7-lane within 8
    return v;
}

__global__ __launch_bounds__(64, 1) void xaj_kernel(
    const float* __restrict__ x,     // (365, 2000, 3)
    const float* __restrict__ prm,   // (2000, 12, 8)
    float* __restrict__ out)         // (365, 2000, 5)
{
    constexpr int Nstep = 365, Ngrid = 2000;
    constexpr int xstride = Ngrid * 3;
    constexpr int K = 8;             // steps per block (load/store burst unit)
    const int tid = blockIdx.x * 64 + threadIdx.x;   // grid=250, block=64 -> exactly 16000
    const int g = tid >> 3;
    const int m = tid & 7;

    const float lo[12] = {0.3f,0.0f,0.01f,0.01f,0.01f,0.09f,0.01f,0.0f,0.01f,0.01f,0.0f,0.0f};
    const float hi[12] = {2.0f,5.0f,100.0f,100.0f,200.0f,1.0f,100.0f,10.0f,0.7f,0.7f,0.998f,0.998f};
    float p[12];
    const float* pb = prm + (size_t)g * 96 + m;
#pragma unroll
    for (int i = 0; i < 12; ++i)
        p[i] = lo[i] + pb[i * 8] * (hi[i] - lo[i]);

    const float KE=p[0], B=p[1], WUM=p[2], WLM=p[3], WM=p[4], C=p[5],
                SM=p[6], EX=p[7], KI_=p[8], KG_=p[9], CI=p[10], CG=p[11];

    // loop-invariant derived constants
    const float wdm  = fmaxf(WM - WUM - WLM, 0.f);
    const float sumk = KI_ + KG_;
    const float nrm  = (1.f - PRECS) / (sumk + PRECS);
    const float KI   = (sumk < 1.f) ? KI_ : KI_ * nrm;
    const float KG   = (sumk < 1.f) ? KG_ : KG_ * nrm;
    const float expB = 1.f + B,  invB  = 1.f / expB;
    const float WMM  = WM * expB;
    const float expEX= 1.f + EX, invEX = 1.f / expEX;
    const float SMM  = SM * expEX;
    const float inv_WLM = 1.f / (WLM + PRECS);
    const float inv_WM  = 1.f / (WM  + PRECS);
    const float inv_WMM = 1.f / (WMM + PRECS);
    const float inv_SM  = 1.f / (SM  + PRECS);
    const float inv_SMM = 1.f / (SMM + PRECS);
    const float oneK = 1.f - KI - KG;
    const float omCI = 1.f - CI, omCG = 1.f - CG;
    const float CWLM = C * WLM;
    const float inv1p = 1.f / (1.f + PRECS);
    // exact floor of ratio_s when S_eq hits the SM clamp: 1 - SM*inv_SM
    const float eps2  = fmaxf(PRECS, fmaf(-SM, inv_SM, 1.f));

    // per-lane output weights: col = min(m,4); lanes 4..7 duplicate col 4
    const float wa = (m == 0 || m == 1) ? 0.125f : 0.f;
    const float wb = (m == 0 || m == 2) ? 0.125f : 0.f;
    const float wc = (m == 0 || m == 3) ? 0.125f : 0.f;
    const float wd = (m >= 4) ? 0.125f : 0.f;
    const int   col = (m < 4) ? m : 4;
    float* outp = out + (size_t)g * 5 + col;
    const size_t ostr = (size_t)Ngrid * 5;

    // carry state. W-chain: WU/WL/WD.  S-chain: S, FR0, iFR0, QI, QG.
    float WU=0.001f, WL=0.001f, WD=0.001f;
    float S=0.001f, FR0=0.001f, QI=0.001f, QG=0.001f;
    float iFR0 = frcp(FR0 + PRECS);

    // stash handed from A to B within a step
    float sPE, sRp, sE, sFRn, siFRn;

    const float* xg = x + (size_t)g * 3;

    // ---- A: W-chain for step t. Reads/writes WU,WL,WD only; emits stash. ----
    auto Ablock = [&](float Pt, float PETr) {
        const float PET_t = PETr * KE;
        // evaporation cascade. D = relu(PET - P - WU) is exact:
        // max(PET - min(PET, WU+P), 0) == relu(PET - P - WU)
        const float EU = fminf(PET_t, WU + Pt);
        const float D  = fmaxf(PET_t - Pt - WU, 0.f);
        // WL-only side (off D's path)
        const float we = fmaxf(WL - CWLM, 0.f);
        const float wr = we * frcp(we + 1.f);
        const float cwet = wr * WL * inv_WLM;   // wr*EL_wet = cwet*D
        const float omwr = 1.f - wr;
        const float ELdry = fminf(C * D, WL);
        const float EL = fminf(fmaxf(fmaf(omwr, ELdry, cwet * D), 0.f), WL);
        const float ED = fminf(C * fmaxf(D - EL, 0.f), WD);
        const float E  = EU + EL + ED;
        const float PE = fmaxf(Pt - E, 0.f);

        // runoff generation; omr = relu(pow1 - PE/WMM) == relu(1-(PE+A)/WMM)
        // up to eps=PRECS/WMM (R_per error <= PRECS)
        const float W = WU + WL + WD;
        const float base_W = fmaxf(fmaf(-W, inv_WM, 1.f), PRECS);
        const float pw1 = fpow(base_W, invB);
        const float omr = fmaxf(fmaf(-PE, inv_WMM, pw1), 0.f);
        const float R_per = fmaxf(fmaf(WM, fpow(omr, expB), PE + (W - WM)), 0.f);

        // soil-moisture bookkeeping: parallel fill/sub chains + sign select.
        const float dW = Pt - E - R_per;
        const float cum0 = WU + dW;
        const float WUf  = fminf(cum0, WUM);
        const float cum1 = WL + (cum0 - WUf);
        const float WLf  = fminf(cum1, WLM);
        const float cum2 = WD + (cum1 - WLf);
        const float WDf  = fminf(cum2, fmaxf(wdm, WD));
        const float dneg = -dW;
        const float WUs  = fmaxf(WU - dneg, 0.f);
        const float r1   = fmaxf(dneg - WU, 0.f);
        const float WLs  = fmaxf(WL - r1, 0.f);
        const float r2   = fmaxf(r1 - WL, 0.f);
        const float WDs  = fmaxf(WD - r2, 0.f);
        const bool pos = dW >= 0.f;
        WU = pos ? WUf : WUs;
        WL = pos ? WLf : WLs;
        WD = pos ? WDf : WDs;

        // FR candidates for B. rcp(min(aa,1)+PRECS) == max(rcp(aa+PRECS), inv1p)
        const float q  = frcp(PE + PRECS);
        const float aa = R_per * q;
        sFRn  = fminf(aa, 1.f);
        siFRn = fmaxf(frcp(aa + PRECS), inv1p);
        sPE = PE; sRp = R_per; sE = E;
    };

    // ---- B: S-chain for the stashed step + reduction; returns output value ----
    auto Bblock = [&]() -> float {
        const float PE = sPE, R_per = sRp;
        const bool wet = PE > 0.f;
        const float FR  = wet ? sFRn  : FR0;
        const float iFR = wet ? siFRn : iFR0;   // rcp(FR+PRECS), FR0-branch carried free
        const float sf  = S * FR0;              // previous-iteration values: off-chain
        const float sf2 = sf * inv_SM;
        const float S_eq = fminf(sf * iFR, SM);
        // exact refactor: max(1 - min(sf*iFR,SM)*inv_SM, PRECS)
        //              == max(1 - sf2*iFR, max(PRECS, 1-SM*inv_SM))
        const float ratio_s = fmaxf(fmaf(-sf2, iFR, 1.f), eps2);
        const float u   = fpow(ratio_s, invEX);
        // om2 = relu(u - PE/SMM) == relu(1-(PE+AU)/SMM) up to PRECS-level error
        const float om2 = fmaxf(fmaf(-PE, inv_SMM, u), 0.f);
        const float base = (PE - SM) + S_eq;
        float RS = fmaf(SM, fpow(om2, expEX), base) * FR;
        RS = __builtin_amdgcn_fmed3f(RS, 0.f, R_per);   // clamp [0, R_per]
        const float Sn = fminf(fmaf(R_per - RS, iFR, S_eq), SM);
        const float RI = (KI * FR) * Sn;
        const float RG = (KG * FR) * Sn;
        S  = Sn * oneK;
        QI = fmaf(omCI, RI, CI * QI);
        QG = fmaf(omCG, RG, CG * QG);
        FR0 = FR; iFR0 = iFR;

        // mean over mu (8 lanes per grid) on the VALU pipe
        const float u0 = rsum8(RS);
        const float u1 = rsum8(QI);
        const float u2 = rsum8(QG);
        const float u3 = rsum8(sE);
        return fmaf(u0, wa, fmaf(u1, wb, fmaf(u2, wc, u3 * wd)));
    };

    // ping-pong P/PET register blocks. Loads for block i+1 are issued at the
    // top of block i (slack = 8 steps >> HBM latency); the 8 output stores are
    // issued at the END of each block, so they are always YOUNGER than any
    // load the next block waits on -> counted vmcnt waits never drain stores.
    float PA[K], EA[K], PB[K], EB[K], o[K];

#define ISSUE(Pr, Er, BLK)                                              \
    {                                                                   \
        const int _b = (BLK);                                           \
        _Pragma("unroll")                                               \
        for (int k = 0; k < K; ++k) {                                   \
            int _t = _b * K + k;                                        \
            _t = (_t < Nstep) ? _t : Nstep - 1;                         \
            const float* _xq = xg + (size_t)_t * xstride;               \
            Pr[k] = _xq[0];                                             \
            Er[k] = _xq[2];                                             \
        }                                                               \
    }

#define COMPUTE(Pr, Er, T0)                                             \
    {                                                                   \
        const int _t0 = (T0);                                           \
        _Pragma("unroll")                                               \
        for (int k = 0; k < K; ++k) {                                   \
            Ablock(Pr[k], Er[k]);                                       \
            o[k] = Bblock();                                            \
        }                                                               \
        _Pragma("unroll")                                               \
        for (int k = 0; k < K; ++k)                                     \
            if (_t0 + k < Nstep)                                        \
                outp[(size_t)(_t0 + k) * ostr] = o[k];                  \
    }

    // 46 blocks of 8 = 368 padded steps; steps >= 365 are computed with
    // clamped inputs (harmless garbage state) but never stored.
    ISSUE(PA, EA, 0);
    int t0 = 0;
#pragma unroll 1
    for (int it = 0; it < 23; ++it) {
        ISSUE(PB, EB, 2 * it + 1);
        COMPUTE(PA, EA, t0);
        ISSUE(PA, EA, 2 * it + 2);   // last iter: fully clamped, wasted but harmless
        COMPUTE(PB, EB, t0 + K);
        t0 += 2 * K;
    }
#undef ISSUE
#undef COMPUTE
}

extern "C" void kernel_launch(void* const* d_in, const int* in_sizes, int n_in,
                              void* d_out, int out_size, void* d_ws, size_t ws_size,
                              hipStream_t stream) {
    const float* x   = (const float*)d_in[0];
    const float* prm = (const float*)d_in[1];
    float* out = (float*)d_out;
    xaj_kernel<<<250, 64, 0, stream>>>(x, prm, out);
}

// Round 3
// 70.380 us; speedup vs baseline: 1.5412x; 1.5245x over previous
//
#include <hip/hip_runtime.h>

#define PRECS 1e-6f

// raw hardware transcendentals: v_exp_f32 / v_log_f32 (base-2).
// fpow(0, e>0) == 0 exactly: log2(0)=-inf -> exp2(-inf)=0.
__device__ __forceinline__ float fpow(float b, float e) {
    return __builtin_amdgcn_exp2f(e * __builtin_amdgcn_logf(b));
}

__device__ __forceinline__ float frcp(float v) {
    return __builtin_amdgcn_rcpf(v);
}

template <int CTRL>
__device__ __forceinline__ float dpp_mov(float v) {
    return __int_as_float(
        __builtin_amdgcn_update_dpp(0, __float_as_int(v), CTRL, 0xF, 0xF, true));
}

// sum over each 8-lane group, entirely on the VALU pipe (DPP, no LDS)
__device__ __forceinline__ float rsum8(float v) {
    v += dpp_mov<0xB1>(v);   // quad_perm [1,0,3,2]  : lane ^= 1
    v += dpp_mov<0x4E>(v);   // quad_perm [2,3,0,1]  : lane ^= 2
    v += dpp_mov<0x141>(v);  // row_half_mirror      : lane -> 7-lane within 8
    return v;
}

// Wave-specialized: wave 0 runs the W-chain (A) for 64 chains, wave 1 runs the
// S-chain + reduction + store (B) for the same 64 chains, one 8-step block
// behind, through a double-buffered LDS stash. Each wave sits on its own SIMD,
// so the two half-step issue loads run fully in parallel.
__global__ __launch_bounds__(128, 1) void xaj_kernel(
    const float* __restrict__ x,     // (365, 2000, 3)
    const float* __restrict__ prm,   // (2000, 12, 8)
    float* __restrict__ out)         // (365, 2000, 5)
{
    constexpr int Nstep = 365, Ngrid = 2000;
    constexpr int xstride = Ngrid * 3;
    constexpr int K = 8;             // steps per stash block
    constexpr int NB = 46;           // 46*8 = 368 padded steps

    const int wid  = (int)threadIdx.x >> 6;   // 0 = producer (A), 1 = consumer (B)
    const int lane = (int)threadIdx.x & 63;
    const int g = blockIdx.x * 8 + (lane >> 3);   // 250 blocks * 8 grids = 2000
    const int m = lane & 7;

    // stash[buf][k][var][lane]: var-major, lane-minor -> 2-way bank alias only (free)
    __shared__ float stash[2][K][5][64];

    const float lo[12] = {0.3f,0.0f,0.01f,0.01f,0.01f,0.09f,0.01f,0.0f,0.01f,0.01f,0.0f,0.0f};
    const float hi[12] = {2.0f,5.0f,100.0f,100.0f,200.0f,1.0f,100.0f,10.0f,0.7f,0.7f,0.998f,0.998f};
    float p[12];
    const float* pb = prm + (size_t)g * 96 + m;
#pragma unroll
    for (int i = 0; i < 12; ++i)
        p[i] = lo[i] + pb[i * 8] * (hi[i] - lo[i]);

    const float KE=p[0], B=p[1], WUM=p[2], WLM=p[3], WM=p[4], C=p[5],
                SM=p[6], EX=p[7], KI_=p[8], KG_=p[9], CI=p[10], CG=p[11];

    // loop-invariant derived constants (liveness: each wave keeps only its own)
    const float wdm  = fmaxf(WM - WUM - WLM, 0.f);
    const float sumk = KI_ + KG_;
    const float nrm  = (1.f - PRECS) / (sumk + PRECS);
    const float KI   = (sumk < 1.f) ? KI_ : KI_ * nrm;
    const float KG   = (sumk < 1.f) ? KG_ : KG_ * nrm;
    const float expB = 1.f + B,  invB  = 1.f / expB;
    const float WMM  = WM * expB;
    const float expEX= 1.f + EX, invEX = 1.f / expEX;
    const float SMM  = SM * expEX;
    const float inv_WLM = 1.f / (WLM + PRECS);
    const float inv_WM  = 1.f / (WM  + PRECS);
    const float inv_WMM = 1.f / (WMM + PRECS);
    const float inv_SM  = 1.f / (SM  + PRECS);
    const float inv_SMM = 1.f / (SMM + PRECS);
    const float oneK = 1.f - KI - KG;
    const float omCI = 1.f - CI, omCG = 1.f - CG;
    const float CWLM = C * WLM;
    const float inv1p = 1.f / (1.f + PRECS);
    // exact floor of ratio_s when S_eq hits the SM clamp: 1 - SM*inv_SM
    const float eps2  = fmaxf(PRECS, fmaf(-SM, inv_SM, 1.f));

    if (wid == 0) {
        // ================= producer: W-chain =================
        float WU = 0.001f, WL = 0.001f, WD = 0.001f;
        const float* xg = x + (size_t)g * 3;
        float PA[K], EA[K], PB_[K], EB_[K];

#define ISSUE(Pr, Er, BLK)                                              \
        {                                                               \
            const int _b = (BLK);                                       \
            _Pragma("unroll")                                           \
            for (int k = 0; k < K; ++k) {                               \
                int _t = _b * K + k;                                    \
                _t = (_t < Nstep) ? _t : Nstep - 1;                     \
                const float* _xq = xg + (size_t)_t * xstride;           \
                Pr[k] = _xq[0];                                         \
                Er[k] = _xq[2];                                         \
            }                                                           \
        }

#define PRODUCE(Pr, Er, BUF)                                            \
        {                                                               \
            _Pragma("unroll")                                           \
            for (int k = 0; k < K; ++k) {                               \
                const float Pt = Pr[k], PETr = Er[k];                   \
                const float PET_t = PETr * KE;                          \
                /* evap cascade; D = relu(PET-P-WU) is exact */         \
                const float EU = fminf(PET_t, WU + Pt);                 \
                const float D  = fmaxf(PET_t - Pt - WU, 0.f);           \
                const float we = fmaxf(WL - CWLM, 0.f);                 \
                const float wr = we * frcp(we + 1.f);                   \
                const float cwet = wr * WL * inv_WLM;                   \
                const float ELdry = fminf(C * D, WL);                   \
                const float EL = fminf(fmaxf(fmaf(1.f - wr, ELdry, cwet * D), 0.f), WL); \
                const float ED = fminf(C * fmaxf(D - EL, 0.f), WD);     \
                const float E  = EU + EL + ED;                          \
                const float PE = fmaxf(Pt - E, 0.f);                    \
                /* runoff; omr = relu(pow1 - PE/WMM), err <= PRECS */   \
                const float W = WU + WL + WD;                           \
                const float base_W = fmaxf(fmaf(-W, inv_WM, 1.f), PRECS); \
                const float pw1 = fpow(base_W, invB);                   \
                const float omr = fmaxf(fmaf(-PE, inv_WMM, pw1), 0.f);  \
                const float R_per = fmaxf(fmaf(WM, fpow(omr, expB), PE + (W - WM)), 0.f); \
                /* exact med3 clamp cascade (both signs of dW) */       \
                const float dW = Pt - E - R_per;                        \
                const float capD = fmaxf(wdm, WD);                      \
                const float cum0 = WU + dW;                             \
                const float WUn  = __builtin_amdgcn_fmed3f(cum0, 0.f, WUM); \
                const float cum1 = WL + (cum0 - WUn);                   \
                const float WLn  = __builtin_amdgcn_fmed3f(cum1, 0.f, WLM); \
                const float cum2 = WD + (cum1 - WLn);                   \
                const float WDn  = __builtin_amdgcn_fmed3f(cum2, 0.f, capD); \
                WU = WUn; WL = WLn; WD = WDn;                           \
                /* FR candidates for B */                               \
                const float q  = frcp(PE + PRECS);                      \
                const float aa = R_per * q;                             \
                const float sFRn  = fminf(aa, 1.f);                     \
                const float siFRn = fmaxf(frcp(aa + PRECS), inv1p);     \
                stash[BUF][k][0][lane] = PE;                            \
                stash[BUF][k][1][lane] = R_per;                         \
                stash[BUF][k][2][lane] = E;                             \
                stash[BUF][k][3][lane] = sFRn;                          \
                stash[BUF][k][4][lane] = siFRn;                         \
            }                                                           \
        }

        ISSUE(PA, EA, 0);
#pragma unroll 1
        for (int it = 0; it < 23; ++it) {
            ISSUE(PB_, EB_, 2 * it + 1);
            PRODUCE(PA, EA, 0);          // block 2*it   -> buf 0
            __syncthreads();
            ISSUE(PA, EA, 2 * it + 2);   // last iter: clamped, harmless
            PRODUCE(PB_, EB_, 1);        // block 2*it+1 -> buf 1
            __syncthreads();
        }
        __syncthreads();                 // consumer drains the last block
#undef ISSUE
#undef PRODUCE
    } else {
        // ================= consumer: S-chain + reduce + store =================
        float S = 0.001f, FR0 = 0.001f, QI = 0.001f, QG = 0.001f;
        float iFR0 = frcp(FR0 + PRECS);

        // per-lane output weights: col = min(m,4); lanes 4..7 duplicate col 4
        const float wa = (m == 0 || m == 1) ? 0.125f : 0.f;
        const float wb = (m == 0 || m == 2) ? 0.125f : 0.f;
        const float wc = (m == 0 || m == 3) ? 0.125f : 0.f;
        const float wd = (m >= 4) ? 0.125f : 0.f;
        const int   col = (m < 4) ? m : 4;
        float* outp = out + (size_t)g * 5 + col;
        const size_t ostr = (size_t)Ngrid * 5;

#define CONSUME(BUF, T0)                                                \
        {                                                               \
            const int _t0 = (T0);                                       \
            _Pragma("unroll")                                           \
            for (int k = 0; k < K; ++k) {                               \
                const float PE    = stash[BUF][k][0][lane];             \
                const float R_per = stash[BUF][k][1][lane];             \
                const float sE    = stash[BUF][k][2][lane];             \
                const float sFRn  = stash[BUF][k][3][lane];             \
                const float siFRn = stash[BUF][k][4][lane];             \
                const bool wet = PE > 0.f;                              \
                const float FR  = wet ? sFRn  : FR0;                    \
                const float iFR = wet ? siFRn : iFR0;                   \
                const float sf  = S * FR0;   /* prev-step values */     \
                const float sf2 = sf * inv_SM;                          \
                const float S_eq = fminf(sf * iFR, SM);                 \
                const float ratio_s = fmaxf(fmaf(-sf2, iFR, 1.f), eps2);\
                const float u   = fpow(ratio_s, invEX);                 \
                const float om2 = fmaxf(fmaf(-PE, inv_SMM, u), 0.f);    \
                const float base = (PE - SM) + S_eq;                    \
                float RS = fmaf(SM, fpow(om2, expEX), base) * FR;       \
                RS = __builtin_amdgcn_fmed3f(RS, 0.f, R_per);           \
                const float Sn = fminf(fmaf(R_per - RS, iFR, S_eq), SM);\
                const float RI = (KI * FR) * Sn;                        \
                const float RG = (KG * FR) * Sn;                        \
                S  = Sn * oneK;                                         \
                QI = fmaf(omCI, RI, CI * QI);                           \
                QG = fmaf(omCG, RG, CG * QG);                           \
                FR0 = FR; iFR0 = iFR;                                   \
                const float u0 = rsum8(RS);                             \
                const float u1 = rsum8(QI);                             \
                const float u2 = rsum8(QG);                             \
                const float u3 = rsum8(sE);                             \
                const float v = fmaf(u0, wa, fmaf(u1, wb, fmaf(u2, wc, u3 * wd))); \
                if (_t0 + k < Nstep)                                    \
                    outp[(size_t)(_t0 + k) * ostr] = v;                 \
            }                                                           \
        }

        __syncthreads();                 // wait for block 0
#pragma unroll 1
        for (int it = 0; it < 23; ++it) {
            CONSUME(0, (2 * it) * K);
            __syncthreads();
            CONSUME(1, (2 * it + 1) * K);
            __syncthreads();
        }
#undef CONSUME
    }
}

extern "C" void kernel_launch(void* const* d_in, const int* in_sizes, int n_in,
                              void* d_out, int out_size, void* d_ws, size_t ws_size,
                              hipStream_t stream) {
    const float* x   = (const float*)d_in[0];
    const float* prm = (const float*)d_in[1];
    float* out = (float*)d_out;
    xaj_kernel<<<250, 128, 0, stream>>>(x, prm, out);
}

// Round 4
// 59.371 us; speedup vs baseline: 1.8270x; 1.1854x over previous
//
#include <hip/hip_runtime.h>

#define PRECS 1e-6f

// raw hardware transcendentals: v_exp_f32 / v_log_f32 (base-2).
// fpow(0, e>0) == 0 exactly: log2(0)=-inf -> exp2(-inf)=0.
__device__ __forceinline__ float fpow(float b, float e) {
    return __builtin_amdgcn_exp2f(e * __builtin_amdgcn_logf(b));
}

__device__ __forceinline__ float frcp(float v) {
    return __builtin_amdgcn_rcpf(v);
}

template <int CTRL>
__device__ __forceinline__ float dpp_mov(float v) {
    return __int_as_float(
        __builtin_amdgcn_update_dpp(0, __float_as_int(v), CTRL, 0xF, 0xF, true));
}

// sum over each 8-lane group, entirely on the VALU pipe (DPP, no LDS)
__device__ __forceinline__ float rsum8(float v) {
    v += dpp_mov<0xB1>(v);   // quad_perm [1,0,3,2]  : lane ^= 1
    v += dpp_mov<0x4E>(v);   // quad_perm [2,3,0,1]  : lane ^= 2
    v += dpp_mov<0x141>(v);  // row_half_mirror      : lane -> 7-lane within 8
    return v;
}

// 3-stage wave-specialized pipeline over 8-step blocks:
//   wave 0 (A): W-chain (evap cascade, runoff gen, soil bookkeeping)
//   wave 1 (B): S-chain (free-water reservoir), one block behind A
//   wave 2 (C): 8-lane reductions + global stores, one block behind B
// Handoffs are single float4 LDS slots per step (ds_write_b128 / b128 bulk
// reads hoisted into registers right after the barrier), double-buffered.
__global__ __launch_bounds__(192, 1) void xaj_kernel(
    const float* __restrict__ x,     // (365, 2000, 3)
    const float* __restrict__ prm,   // (2000, 12, 8)
    float* __restrict__ out)         // (365, 2000, 5)
{
    constexpr int Nstep = 365, Ngrid = 2000;
    constexpr int xstride = Ngrid * 3;
    constexpr int K = 8;             // steps per pipeline block
    constexpr int NBLK = 46;         // 46*8 = 368 padded steps

    const int wid  = (int)threadIdx.x >> 6;   // 0=A, 1=B, 2=C
    const int lane = (int)threadIdx.x & 63;
    const int g = blockIdx.x * 8 + (lane >> 3);   // 250 blocks * 8 grids = 2000
    const int m = lane & 7;

    // stage handoffs: stA = {PE, R_per, E, pad}, stB = {RS, QI, QG, E}
    __shared__ float4 stA[2][K][64];
    __shared__ float4 stB[2][K][64];

    const float lo[12] = {0.3f,0.0f,0.01f,0.01f,0.01f,0.09f,0.01f,0.0f,0.01f,0.01f,0.0f,0.0f};
    const float hi[12] = {2.0f,5.0f,100.0f,100.0f,200.0f,1.0f,100.0f,10.0f,0.7f,0.7f,0.998f,0.998f};
    float p[12];
    const float* pb = prm + (size_t)g * 96 + m;
#pragma unroll
    for (int i = 0; i < 12; ++i)
        p[i] = lo[i] + pb[i * 8] * (hi[i] - lo[i]);

    const float KE=p[0], B=p[1], WUM=p[2], WLM=p[3], WM=p[4], C=p[5],
                SM=p[6], EX=p[7], KI_=p[8], KG_=p[9], CI=p[10], CG=p[11];

    // loop-invariant derived constants
    const float wdm  = fmaxf(WM - WUM - WLM, 0.f);
    const float sumk = KI_ + KG_;
    const float nrm  = (1.f - PRECS) / (sumk + PRECS);
    const float KI   = (sumk < 1.f) ? KI_ : KI_ * nrm;
    const float KG   = (sumk < 1.f) ? KG_ : KG_ * nrm;
    const float expB = 1.f + B,  invB  = 1.f / expB;
    const float WMM  = WM * expB;
    const float expEX= 1.f + EX, invEX = 1.f / expEX;
    const float SMM  = SM * expEX;
    const float inv_WLM = 1.f / (WLM + PRECS);
    const float inv_WM  = 1.f / (WM  + PRECS);
    const float inv_WMM = 1.f / (WMM + PRECS);
    const float inv_SM  = 1.f / (SM  + PRECS);
    const float inv_SMM = 1.f / (SMM + PRECS);
    const float oneK = 1.f - KI - KG;
    const float omCI = 1.f - CI, omCG = 1.f - CG;
    const float CWLM = C * WLM;
    const float inv1p = 1.f / (1.f + PRECS);
    // exact floor of ratio_s when S_eq hits the SM clamp: 1 - SM*inv_SM
    const float eps2  = fmaxf(PRECS, fmaf(-SM, inv_SM, 1.f));

    // ---------------- stage bodies ----------------
    // A state
    float WU = 0.001f, WL = 0.001f, WD = 0.001f;
    // B state
    float S = 0.001f, FR0 = 0.001f, QI = 0.001f, QG = 0.001f;
    float iFR0 = frcp(FR0 + PRECS);
    // C output setup: col = min(m,4); lanes 4..7 duplicate col 4
    const float wa = (m == 0 || m == 1) ? 0.125f : 0.f;
    const float wb = (m == 0 || m == 2) ? 0.125f : 0.f;
    const float wc = (m == 0 || m == 3) ? 0.125f : 0.f;
    const float wd = (m >= 4) ? 0.125f : 0.f;
    const int   col = (m < 4) ? m : 4;
    float* outp = out + (size_t)g * 5 + col;
    const size_t ostr = (size_t)Ngrid * 5;

    const float* xg = x + (size_t)g * 3;
    float PA[K], EA[K], PB_[K], EB_[K];

    auto ISSUE = [&](float* Pr, float* Er, int blk) {
#pragma unroll
        for (int k = 0; k < K; ++k) {
            int t = blk * K + k;
            t = (t < Nstep) ? t : Nstep - 1;
            const float* xq = xg + (size_t)t * xstride;
            Pr[k] = xq[0];
            Er[k] = xq[2];
        }
    };

    auto PRODUCE = [&](const float* Pr, const float* Er, float4* sa) {
#pragma unroll
        for (int k = 0; k < K; ++k) {
            const float Pt = Pr[k], PETr = Er[k];
            const float PET_t = PETr * KE;
            // evap cascade; D = relu(PET-P-WU) is exact
            const float EU = fminf(PET_t, WU + Pt);
            const float D  = fmaxf(PET_t - Pt - WU, 0.f);
            const float we = fmaxf(WL - CWLM, 0.f);
            const float wr = we * frcp(we + 1.f);
            const float cwet = wr * WL * inv_WLM;
            const float ELdry = fminf(C * D, WL);
            const float EL = fminf(fmaxf(fmaf(1.f - wr, ELdry, cwet * D), 0.f), WL);
            const float ED = fminf(C * fmaxf(D - EL, 0.f), WD);
            const float E  = EU + EL + ED;
            const float PE = fmaxf(Pt - E, 0.f);
            // runoff; omr = relu(pow1 - PE/WMM), err <= PRECS
            const float W = WU + WL + WD;
            const float base_W = fmaxf(fmaf(-W, inv_WM, 1.f), PRECS);
            const float pw1 = fpow(base_W, invB);
            const float omr = fmaxf(fmaf(-PE, inv_WMM, pw1), 0.f);
            const float R_per = fmaxf(fmaf(WM, fpow(omr, expB), PE + (W - WM)), 0.f);
            // exact med3 clamp cascade (both signs of dW)
            const float dW = Pt - E - R_per;
            const float capD = fmaxf(wdm, WD);
            const float cum0 = WU + dW;
            const float WUn  = __builtin_amdgcn_fmed3f(cum0, 0.f, WUM);
            const float cum1 = WL + (cum0 - WUn);
            const float WLn  = __builtin_amdgcn_fmed3f(cum1, 0.f, WLM);
            const float cum2 = WD + (cum1 - WLn);
            const float WDn  = __builtin_amdgcn_fmed3f(cum2, 0.f, capD);
            WU = WUn; WL = WLn; WD = WDn;
            sa[k * 64 + lane] = make_float4(PE, R_per, E, 0.f);
        }
    };

    auto BSTEP = [&](const float4* sa, float4* sb) {
        float4 ra[K];
#pragma unroll
        for (int k = 0; k < K; ++k)
            ra[k] = sa[k * 64 + lane];
        // FR candidates for all K steps up front (off the carried chain).
        // rcp(min(aa,1)+PRECS) == max(rcp(aa+PRECS), inv1p)
        float FRn[K], iFRn[K];
#pragma unroll
        for (int k = 0; k < K; ++k) {
            const float q  = frcp(ra[k].x + PRECS);
            const float aa = ra[k].y * q;
            FRn[k]  = fminf(aa, 1.f);
            iFRn[k] = fmaxf(frcp(aa + PRECS), inv1p);
        }
#pragma unroll
        for (int k = 0; k < K; ++k) {
            const float PE = ra[k].x, R_per = ra[k].y;
            const bool wet = PE > 0.f;
            const float FR  = wet ? FRn[k]  : FR0;
            const float iFR = wet ? iFRn[k] : iFR0;
            const float sf  = S * FR0;      // prev-step values: off-chain
            const float sf2 = sf * inv_SM;
            const float S_eq = fminf(sf * iFR, SM);
            const float ratio_s = fmaxf(fmaf(-sf2, iFR, 1.f), eps2);
            const float u   = fpow(ratio_s, invEX);
            const float om2 = fmaxf(fmaf(-PE, inv_SMM, u), 0.f);
            const float base = (PE - SM) + S_eq;
            float RS = fmaf(SM, fpow(om2, expEX), base) * FR;
            RS = __builtin_amdgcn_fmed3f(RS, 0.f, R_per);
            const float Sn = fminf(fmaf(R_per - RS, iFR, S_eq), SM);
            const float RI = (KI * FR) * Sn;
            const float RG = (KG * FR) * Sn;
            S  = Sn * oneK;
            QI = fmaf(omCI, RI, CI * QI);
            QG = fmaf(omCG, RG, CG * QG);
            FR0 = FR; iFR0 = iFR;
            sb[k * 64 + lane] = make_float4(RS, QI, QG, ra[k].z);
        }
    };

    auto CSTEP = [&](const float4* sb, int blk) {
        float4 rb[K];
#pragma unroll
        for (int k = 0; k < K; ++k)
            rb[k] = sb[k * 64 + lane];
        const int t0 = blk * K;
#pragma unroll
        for (int k = 0; k < K; ++k) {
            const float u0 = rsum8(rb[k].x);
            const float u1 = rsum8(rb[k].y);
            const float u2 = rsum8(rb[k].z);
            const float u3 = rsum8(rb[k].w);
            const float v = fmaf(u0, wa, fmaf(u1, wb, fmaf(u2, wc, u3 * wd)));
            if (t0 + k < Nstep)
                outp[(size_t)(t0 + k) * ostr] = v;
        }
    };

    // ---------------- phase loop ----------------
    // phase p: A produces block p -> stA[p&1] (p < 46)
    //          B consumes block p-1 from stA[(p-1)&1] -> stB[(p-1)&1] (1<=p<=46)
    //          C consumes block p-2 from stB[(p-2)&1] (2<=p<=47)
    // 48 phases = 24 iterations x 2 (parities static for A's reg ping-pong).
    if (wid == 0) ISSUE(PA, EA, 0);

#pragma unroll 1
    for (int it = 0; it < 24; ++it) {
        const int p0 = 2 * it, p1 = 2 * it + 1;
        if (wid == 0) {
            if (p0 < NBLK) {
                ISSUE(PB_, EB_, (p0 + 1 < NBLK) ? p0 + 1 : NBLK - 1);
                PRODUCE(PA, EA, &stA[0][0][0]);
            }
        } else if (wid == 1) {
            if (p0 >= 2 && p0 <= NBLK)               // block p0-1 (odd) from buf 1
                BSTEP(&stA[1][0][0], &stB[1][0][0]);
        } else {
            if (p0 >= 2)                             // block p0-2 (even) from buf 0
                CSTEP(&stB[0][0][0], p0 - 2);
        }
        __syncthreads();
        if (wid == 0) {
            if (p1 < NBLK) {
                ISSUE(PA, EA, (p1 + 1 < NBLK) ? p1 + 1 : NBLK - 1);
                PRODUCE(PB_, EB_, &stA[1][0][0]);
            }
        } else if (wid == 1) {
            if (p1 <= NBLK)                          // block p1-1 (even) from buf 0
                BSTEP(&stA[0][0][0], &stB[0][0][0]);
        } else {
            if (p1 >= 3)                             // block p1-2 (odd) from buf 1
                CSTEP(&stB[1][0][0], p1 - 2);
        }
        __syncthreads();
    }
}

extern "C" void kernel_launch(void* const* d_in, const int* in_sizes, int n_in,
                              void* d_out, int out_size, void* d_ws, size_t ws_size,
                              hipStream_t stream) {
    const float* x   = (const float*)d_in[0];
    const float* prm = (const float*)d_in[1];
    float* out = (float*)d_out;
    xaj_kernel<<<250, 192, 0, stream>>>(x, prm, out);
}

// Round 5
// 58.073 us; speedup vs baseline: 1.8678x; 1.0223x over previous
//
#include <hip/hip_runtime.h>

#define PRECS 1e-6f

// raw hardware transcendentals: v_exp_f32 / v_log_f32 (base-2).
// fpow(0, e>0) == 0 exactly: log2(0)=-inf -> exp2(-inf)=0.
__device__ __forceinline__ float fpow(float b, float e) {
    return __builtin_amdgcn_exp2f(e * __builtin_amdgcn_logf(b));
}

__device__ __forceinline__ float frcp(float v) {
    return __builtin_amdgcn_rcpf(v);
}

template <int CTRL>
__device__ __forceinline__ float dpp_mov(float v) {
    return __int_as_float(
        __builtin_amdgcn_update_dpp(0, __float_as_int(v), CTRL, 0xF, 0xF, true));
}

// sum over each 8-lane group, entirely on the VALU pipe (DPP, no LDS)
__device__ __forceinline__ float rsum8(float v) {
    v += dpp_mov<0xB1>(v);   // quad_perm [1,0,3,2]  : lane ^= 1
    v += dpp_mov<0x4E>(v);   // quad_perm [2,3,0,1]  : lane ^= 2
    v += dpp_mov<0x141>(v);  // row_half_mirror      : lane -> 7-lane within 8
    return v;
}

// 3-stage wave-specialized pipeline over 16-step blocks:
//   wave 0 (A): W-chain only (evap cascade, runoff gen, soil bookkeeping)
//   wave 1 (B): S-chain (free-water reservoir), one block behind A
//   wave 2 (C): input loader (block p+1) + QI/QG EMA + reductions + stores
//               (block p-2)
// A has ZERO global memory traffic in steady state; C hides HBM load latency
// under its reduction work. All handoffs are b64/b128 LDS bulk transfers.
__global__ __launch_bounds__(192, 1) void xaj_kernel(
    const float* __restrict__ x,     // (365, 2000, 3)
    const float* __restrict__ prm,   // (2000, 12, 8)
    float* __restrict__ out)         // (365, 2000, 5)
{
    constexpr int Nstep = 365, Ngrid = 2000;
    constexpr int xstride = Ngrid * 3;
    constexpr int K = 16;            // steps per pipeline block
    constexpr int NBLK = 23;         // 23*16 = 368 padded steps

    const int wid  = (int)threadIdx.x >> 6;   // 0=A, 1=B, 2=C
    const int lane = (int)threadIdx.x & 63;
    const int g = blockIdx.x * 8 + (lane >> 3);   // 250 blocks * 8 grids = 2000
    const int m = lane & 7;

    __shared__ float2 stIn[2][K][64];   // {P, PET*KE}     (C -> A)
    __shared__ float4 stA[2][K][64];    // {PE, R_per, E, -}  (A -> B)
    __shared__ float4 stB[2][K][64];    // {RS, FR*Sn, E, -}  (B -> C)

    const float lo[12] = {0.3f,0.0f,0.01f,0.01f,0.01f,0.09f,0.01f,0.0f,0.01f,0.01f,0.0f,0.0f};
    const float hi[12] = {2.0f,5.0f,100.0f,100.0f,200.0f,1.0f,100.0f,10.0f,0.7f,0.7f,0.998f,0.998f};
    float p[12];
    const float* pb = prm + (size_t)g * 96 + m;
#pragma unroll
    for (int i = 0; i < 12; ++i)
        p[i] = lo[i] + pb[i * 8] * (hi[i] - lo[i]);

    const float KE=p[0], B=p[1], WUM=p[2], WLM=p[3], WM=p[4], C=p[5],
                SM=p[6], EX=p[7], KI_=p[8], KG_=p[9], CI=p[10], CG=p[11];

    // loop-invariant derived constants
    const float wdm  = fmaxf(WM - WUM - WLM, 0.f);
    const float sumk = KI_ + KG_;
    const float nrm  = (1.f - PRECS) / (sumk + PRECS);
    const float KI   = (sumk < 1.f) ? KI_ : KI_ * nrm;
    const float KG   = (sumk < 1.f) ? KG_ : KG_ * nrm;
    const float expB = 1.f + B,  invB  = 1.f / expB;
    const float WMM  = WM * expB;
    const float expEX= 1.f + EX, invEX = 1.f / expEX;
    const float SMM  = SM * expEX;
    const float inv_WLM = 1.f / (WLM + PRECS);
    const float inv_WM  = 1.f / (WM  + PRECS);
    const float inv_WMM = 1.f / (WMM + PRECS);
    const float inv_SM  = 1.f / (SM  + PRECS);
    const float inv_SMM = 1.f / (SMM + PRECS);
    const float oneK = 1.f - KI - KG;
    const float omCI = 1.f - CI, omCG = 1.f - CG;
    const float CWLM = C * WLM;
    const float inv1p = 1.f / (1.f + PRECS);
    // exact floor of ratio_s when S_eq hits the SM clamp: 1 - SM*inv_SM
    const float eps2  = fmaxf(PRECS, fmaf(-SM, inv_SM, 1.f));

    // -------- per-stage carried state (exclusive per wave path) --------
    float WU = 0.001f, WL = 0.001f, WD = 0.001f;          // A
    float S = 0.001f, FR0 = 0.001f;                       // B
    float iFR0 = frcp(FR0 + PRECS);                       // B
    float QI = 0.001f, QG = 0.001f;                       // C
    const float cKI = omCI * KI, cKG = omCG * KG;         // C
    const float wa = (m == 0 || m == 1) ? 0.125f : 0.f;   // C output weights
    const float wb = (m == 0 || m == 2) ? 0.125f : 0.f;
    const float wc = (m == 0 || m == 3) ? 0.125f : 0.f;
    const float wd = (m >= 4) ? 0.125f : 0.f;
    const int   col = (m < 4) ? m : 4;
    float* outp = out + (size_t)g * 5 + col;
    const size_t ostr = (size_t)Ngrid * 5;
    const float* xg = x + (size_t)g * 3;
    float Pr[K], Er[K];                                   // C load staging

    // ---------------- stage bodies ----------------
    auto ASTEP = [&](int buf) {
        float2 rin[K];
#pragma unroll
        for (int k = 0; k < K; ++k)
            rin[k] = stIn[buf][k][lane];
#pragma unroll
        for (int k = 0; k < K; ++k) {
            const float Pt = rin[k].x, PET_t = rin[k].y;
            // evap cascade; D = relu(PET-P-WU) is exact
            const float EU = fminf(PET_t, WU + Pt);
            const float D  = fmaxf(PET_t - Pt - WU, 0.f);
            const float we = fmaxf(WL - CWLM, 0.f);
            const float wr = we * frcp(we + 1.f);
            const float cwet = wr * WL * inv_WLM;
            const float ELdry = fminf(C * D, WL);
            const float EL = fminf(fmaxf(fmaf(1.f - wr, ELdry, cwet * D), 0.f), WL);
            const float ED = fminf(C * fmaxf(D - EL, 0.f), WD);
            const float E  = EU + EL + ED;
            const float PE = fmaxf(Pt - E, 0.f);
            // runoff; omr = relu(pw1 - PE/WMM), err <= PRECS
            const float W = WU + WL + WD;
            const float base_W = fmaxf(fmaf(-W, inv_WM, 1.f), PRECS);
            const float pw1 = fpow(base_W, invB);
            const float omr = fmaxf(fmaf(-PE, inv_WMM, pw1), 0.f);
            const float R_per = fmaxf(fmaf(WM, fpow(omr, expB), PE + (W - WM)), 0.f);
            // exact med3 clamp cascade (both signs of dW)
            const float dW = Pt - E - R_per;
            const float capD = fmaxf(wdm, WD);
            const float cum0 = WU + dW;
            const float WUn  = __builtin_amdgcn_fmed3f(cum0, 0.f, WUM);
            const float cum1 = WL + (cum0 - WUn);
            const float WLn  = __builtin_amdgcn_fmed3f(cum1, 0.f, WLM);
            const float cum2 = WD + (cum1 - WLn);
            const float WDn  = __builtin_amdgcn_fmed3f(cum2, 0.f, capD);
            WU = WUn; WL = WLn; WD = WDn;
            stA[buf][k][lane] = make_float4(PE, R_per, E, 0.f);
        }
    };

    auto BSTEP = [&](int buf) {
        float4 ra[K];
#pragma unroll
        for (int k = 0; k < K; ++k)
            ra[k] = stA[buf][k][lane];
        // FR candidates for all K steps up front (off the carried chain).
        // rcp(min(aa,1)+PRECS) == max(rcp(aa+PRECS), inv1p)
        float FRn[K], iFRn[K];
#pragma unroll
        for (int k = 0; k < K; ++k) {
            const float q  = frcp(ra[k].x + PRECS);
            const float aa = ra[k].y * q;
            FRn[k]  = fminf(aa, 1.f);
            iFRn[k] = fmaxf(frcp(aa + PRECS), inv1p);
        }
#pragma unroll
        for (int k = 0; k < K; ++k) {
            const float PE = ra[k].x, R_per = ra[k].y;
            const bool wet = PE > 0.f;
            const float FR  = wet ? FRn[k]  : FR0;
            const float iFR = wet ? iFRn[k] : iFR0;
            const float sf  = S * FR0;      // prev-step values: off-chain
            const float sf2 = sf * inv_SM;
            const float S_eq = fminf(sf * iFR, SM);
            const float ratio_s = fmaxf(fmaf(-sf2, iFR, 1.f), eps2);
            const float u   = fpow(ratio_s, invEX);
            const float om2 = fmaxf(fmaf(-PE, inv_SMM, u), 0.f);
            const float base = (PE - SM) + S_eq;
            float RS = fmaf(SM, fpow(om2, expEX), base) * FR;
            RS = __builtin_amdgcn_fmed3f(RS, 0.f, R_per);
            const float Sn = fminf(fmaf(R_per - RS, iFR, S_eq), SM);
            S  = Sn * oneK;
            FR0 = FR; iFR0 = iFR;
            stB[buf][k][lane] = make_float4(RS, FR * Sn, ra[k].z, 0.f);
        }
    };

    auto CISSUE = [&](int blk) {
#pragma unroll
        for (int k = 0; k < K; ++k) {
            int t = blk * K + k;
            t = (t < Nstep) ? t : Nstep - 1;
            const float* xq = xg + (size_t)t * xstride;
            Pr[k] = xq[0];
            Er[k] = xq[2];
        }
    };
    auto CWRITE = [&](int buf) {
#pragma unroll
        for (int k = 0; k < K; ++k)
            stIn[buf][k][lane] = make_float2(Pr[k], Er[k] * KE);
    };
    auto CRED = [&](int buf, int q) {
        float4 rb[K];
#pragma unroll
        for (int k = 0; k < K; ++k)
            rb[k] = stB[buf][k][lane];
        const int t0 = q * K;
#pragma unroll
        for (int k = 0; k < K; ++k) {
            // QI/QG EMA carried here: RI = KI*FR*Sn = KI*rb.y, etc.
            QI = fmaf(CI, QI, cKI * rb[k].y);
            QG = fmaf(CG, QG, cKG * rb[k].y);
            const float u0 = rsum8(rb[k].x);
            const float u1 = rsum8(QI);
            const float u2 = rsum8(QG);
            const float u3 = rsum8(rb[k].z);
            const float v = fmaf(u0, wa, fmaf(u1, wb, fmaf(u2, wc, u3 * wd)));
            if (t0 + k < Nstep)
                outp[(size_t)(t0 + k) * ostr] = v;
        }
    };

    // ---------------- phase loop ----------------
    // phase p: A: block p (p<NBLK)        stIn[p&1] -> stA[p&1]
    //          B: block p-1 (1<=p<=NBLK)  stA[(p-1)&1] -> stB[(p-1)&1]
    //          C: load block p+1 -> stIn[(p+1)&1]; reduce block p-2 (p>=2)
    // 26 phases = 13 iterations x 2 (static buffer parity per sub-phase).
    if (wid == 2) { CISSUE(0); CWRITE(0); }   // prime block 0
    __syncthreads();

#pragma unroll 1
    for (int i = 0; i < 13; ++i) {
        const int p0 = 2 * i, p1 = 2 * i + 1;
        if (wid == 0) {
            if (p0 < NBLK) ASTEP(0);
        } else if (wid == 1) {
            if (p0 >= 1 && p0 <= NBLK) BSTEP(1);
        } else {
            const bool ld = (p0 + 1 < NBLK);
            if (ld) CISSUE(p0 + 1);          // issue loads first...
            if (p0 >= 2) CRED(0, p0 - 2);    // ...hide latency under reductions
            if (ld) CWRITE(1);
        }
        __syncthreads();
        if (wid == 0) {
            if (p1 < NBLK) ASTEP(1);
        } else if (wid == 1) {
            if (p1 <= NBLK) BSTEP(0);
        } else {
            const bool ld = (p1 + 1 < NBLK);
            if (ld) CISSUE(p1 + 1);
            if (p1 >= 2) CRED(1, p1 - 2);
            if (ld) CWRITE(0);
        }
        __syncthreads();
    }
}

extern "C" void kernel_launch(void* const* d_in, const int* in_sizes, int n_in,
                              void* d_out, int out_size, void* d_ws, size_t ws_size,
                              hipStream_t stream) {
    const float* x   = (const float*)d_in[0];
    const float* prm = (const float*)d_in[1];
    float* out = (float*)d_out;
    xaj_kernel<<<250, 192, 0, stream>>>(x, prm, out);
}